// Round 1
// baseline (623.947 us; speedup 1.0000x reference)
//
#include <hip/hip_runtime.h>

#define E_TOTAL   500000
#define NN        50000
#define ND        128
#define ED        128
#define HID       256
#define IND       384   /* 2*ND + ED */
#define EB        64
#define NBLOCKS   ((E_TOTAL + EB - 1) / EB)

typedef float  f32x4  __attribute__((ext_vector_type(4)));
typedef short  bf16x8 __attribute__((ext_vector_type(8)));

__device__ __forceinline__ unsigned short f2bf(float f) {
    unsigned int u = __float_as_uint(f);
    u += 0x7FFFu + ((u >> 16) & 1u);   // RNE
    return (unsigned short)(u >> 16);
}

// ---------------- prep: fp32 -> bf16 tables in workspace ----------------
__global__ void prep_nodes(const float* __restrict__ nf, unsigned short* __restrict__ nb) {
    int i = (blockIdx.x * blockDim.x + threadIdx.x) * 4;
    if (i >= NN * ND) return;
    float4 v = *(const float4*)(nf + i);
    ushort4 o;
    o.x = f2bf(v.x); o.y = f2bf(v.y); o.z = f2bf(v.z); o.w = f2bf(v.w);
    *(ushort4*)(nb + i) = o;
}

__global__ void prep_w1(const float* __restrict__ w1, unsigned short* __restrict__ w1t) {
    int i = blockIdx.x * blockDim.x + threadIdx.x;
    if (i >= IND * HID) return;
    int k = i / HID, n = i % HID;
    w1t[n * IND + k] = f2bf(w1[i]);       // W1T[n][k] = W1[k][n]
}

__global__ void prep_w2(const float* __restrict__ w2, unsigned short* __restrict__ w2t) {
    int i = blockIdx.x * blockDim.x + threadIdx.x;
    if (i >= HID * ED) return;
    int k = i / ED, n = i % ED;
    w2t[n * HID + k] = f2bf(w2[i]);       // W2T[n][k] = W2[k][n]
}

// ---------------- main fused kernel ----------------
__global__ __launch_bounds__(256, 2)
void edge_mlp(const float* __restrict__ edgef,
              const int* __restrict__ eidx,
              const unsigned short* __restrict__ nodesb,
              const unsigned short* __restrict__ w1t,
              const unsigned short* __restrict__ w2t,
              const float* __restrict__ b1,
              const float* __restrict__ b2,
              float* __restrict__ out) {
    __shared__ unsigned short At[EB * IND];   // 48 KB, XOR-swizzled rows
    __shared__ unsigned short Ht[EB * HID];   // 32 KB, XOR-swizzled rows

    const int tid  = threadIdx.x;
    const int base = blockIdx.x * EB;
    const int lane = tid & 63;
    const int w    = tid >> 6;       // wave id 0..3
    const int l15  = lane & 15;
    const int lhi  = lane >> 4;      // 0..3

    // ---- stage combined = [h_src | h_dst | h_edge] (bf16) into At ----
    {
        const int* srcI = eidx;
        const int* dstI = eidx + E_TOTAL;
        #pragma unroll
        for (int it = 0; it < 12; ++it) {
            int chunk = tid + it * 256;       // 0..3071 ; 48 x 16B-chunks per row
            int row = chunk / 48;
            int cc  = chunk % 48;
            int e   = base + row;
            int el  = e < E_TOTAL ? e : E_TOTAL - 1;
            bf16x8 val;
            if (cc < 32) {                    // node gather (already bf16)
                int node = (cc < 16) ? srcI[el] : dstI[el];
                int coff = (cc & 15) * 8;
                val = *(const bf16x8*)(nodesb + node * ND + coff);
            } else {                          // edge features fp32 -> bf16
                int coff = (cc - 32) * 8;
                const float* p = edgef + (size_t)el * ED + coff;
                float4 f0 = *(const float4*)p;
                float4 f1 = *(const float4*)(p + 4);
                val[0] = (short)f2bf(f0.x); val[1] = (short)f2bf(f0.y);
                val[2] = (short)f2bf(f0.z); val[3] = (short)f2bf(f0.w);
                val[4] = (short)f2bf(f1.x); val[5] = (short)f2bf(f1.y);
                val[6] = (short)f2bf(f1.z); val[7] = (short)f2bf(f1.w);
            }
            int col = (cc * 8) ^ ((row & 7) * 8);     // swizzle, 16B-aligned
            *(bf16x8*)(At + row * IND + col) = val;
        }
    }
    __syncthreads();

    // ---- GEMM1: H(64x256) = A(64x384) @ W1 ; wave w owns cols [64w,64w+64) ----
    f32x4 acc1[4][4];
    #pragma unroll
    for (int mt = 0; mt < 4; ++mt)
        #pragma unroll
        for (int nt = 0; nt < 4; ++nt)
            acc1[mt][nt] = (f32x4)0.0f;

    #pragma unroll
    for (int ks = 0; ks < 12; ++ks) {
        int c0 = ks * 32 + lhi * 8;
        bf16x8 a[4];
        #pragma unroll
        for (int mt = 0; mt < 4; ++mt) {
            int row = mt * 16 + l15;
            a[mt] = *(const bf16x8*)(At + row * IND + (c0 ^ ((row & 7) * 8)));
        }
        #pragma unroll
        for (int nt = 0; nt < 4; ++nt) {
            int n = w * 64 + nt * 16 + l15;
            bf16x8 b = *(const bf16x8*)(w1t + n * IND + c0);
            #pragma unroll
            for (int mt = 0; mt < 4; ++mt)
                acc1[mt][nt] = __builtin_amdgcn_mfma_f32_16x16x32_bf16(a[mt], b, acc1[mt][nt], 0, 0, 0);
        }
    }

    // ---- bias + relu + bf16 -> Ht (swizzled) ----
    #pragma unroll
    for (int nt = 0; nt < 4; ++nt) {
        int col = w * 64 + nt * 16 + l15;
        float bias = b1[col];
        #pragma unroll
        for (int mt = 0; mt < 4; ++mt) {
            #pragma unroll
            for (int r = 0; r < 4; ++r) {
                float v = acc1[mt][nt][r] + bias;
                v = v > 0.0f ? v : 0.0f;
                int row = mt * 16 + lhi * 4 + r;
                Ht[row * HID + (col ^ ((row & 7) * 8))] = f2bf(v);
            }
        }
    }
    __syncthreads();

    // ---- GEMM2: U(64x128) = H(64x256) @ W2 ; wave w owns cols [32w,32w+32) ----
    f32x4 acc2[4][2];
    #pragma unroll
    for (int mt = 0; mt < 4; ++mt)
        #pragma unroll
        for (int nt = 0; nt < 2; ++nt)
            acc2[mt][nt] = (f32x4)0.0f;

    #pragma unroll
    for (int ks = 0; ks < 8; ++ks) {
        int c0 = ks * 32 + lhi * 8;
        bf16x8 a[4];
        #pragma unroll
        for (int mt = 0; mt < 4; ++mt) {
            int row = mt * 16 + l15;
            a[mt] = *(const bf16x8*)(Ht + row * HID + (c0 ^ ((row & 7) * 8)));
        }
        #pragma unroll
        for (int nt = 0; nt < 2; ++nt) {
            int n = w * 32 + nt * 16 + l15;
            bf16x8 b = *(const bf16x8*)(w2t + n * HID + c0);
            #pragma unroll
            for (int mt = 0; mt < 4; ++mt)
                acc2[mt][nt] = __builtin_amdgcn_mfma_f32_16x16x32_bf16(a[mt], b, acc2[mt][nt], 0, 0, 0);
        }
    }

    // ---- epilogue: out = edge + update + b2 ----
    #pragma unroll
    for (int nt = 0; nt < 2; ++nt) {
        int col = w * 32 + nt * 16 + l15;
        float bias = b2[col];
        #pragma unroll
        for (int mt = 0; mt < 4; ++mt) {
            #pragma unroll
            for (int r = 0; r < 4; ++r) {
                int row = mt * 16 + lhi * 4 + r;
                int e = base + row;
                if (e < E_TOTAL) {
                    size_t off = (size_t)e * ED + col;
                    out[off] = edgef[off] + acc2[mt][nt][r] + bias;
                }
            }
        }
    }
}

extern "C" void kernel_launch(void* const* d_in, const int* in_sizes, int n_in,
                              void* d_out, int out_size, void* d_ws, size_t ws_size,
                              hipStream_t stream) {
    const float* nf   = (const float*)d_in[0];
    const float* ef   = (const float*)d_in[1];
    const int*   eidx = (const int*)d_in[2];
    const float* W1   = (const float*)d_in[3];
    const float* b1   = (const float*)d_in[4];
    const float* W2   = (const float*)d_in[5];
    const float* b2   = (const float*)d_in[6];
    float* out = (float*)d_out;

    unsigned short* nodesb = (unsigned short*)d_ws;            // 12.8 MB
    unsigned short* w1t    = nodesb + NN * ND;                 // 192 KB
    unsigned short* w2t    = w1t + IND * HID;                  // 64 KB

    prep_nodes<<<(NN * ND / 4 + 255) / 256, 256, 0, stream>>>(nf, nodesb);
    prep_w1<<<(IND * HID + 255) / 256, 256, 0, stream>>>(W1, w1t);
    prep_w2<<<(HID * ED + 255) / 256, 256, 0, stream>>>(W2, w2t);
    edge_mlp<<<NBLOCKS, 256, 0, stream>>>(ef, eidx, nodesb, w1t, w2t, b1, b2, out);
}

// Round 2
// 462.835 us; speedup vs baseline: 1.3481x; 1.3481x over previous
//
#include <hip/hip_runtime.h>

#define E_TOTAL   500000
#define NN        50000
#define ND        128
#define ED        128
#define HID       256
#define IND       384   /* 2*ND + ED */
#define EB        64
#define NBLOCKS   ((E_TOTAL + EB - 1) / EB)

typedef float  f32x4  __attribute__((ext_vector_type(4)));
typedef short  bf16x8 __attribute__((ext_vector_type(8)));

__device__ __forceinline__ unsigned short f2bf(float f) {
    unsigned int u = __float_as_uint(f);
    u += 0x7FFFu + ((u >> 16) & 1u);   // RNE
    return (unsigned short)(u >> 16);
}

// ---------------- prep: fp32 -> bf16 tables in workspace ----------------
__global__ void prep_nodes(const float* __restrict__ nf, unsigned short* __restrict__ nb) {
    int i = (blockIdx.x * blockDim.x + threadIdx.x) * 4;
    if (i >= NN * ND) return;
    float4 v = *(const float4*)(nf + i);
    ushort4 o;
    o.x = f2bf(v.x); o.y = f2bf(v.y); o.z = f2bf(v.z); o.w = f2bf(v.w);
    *(ushort4*)(nb + i) = o;
}

__global__ void prep_w1(const float* __restrict__ w1, unsigned short* __restrict__ w1t) {
    int i = blockIdx.x * blockDim.x + threadIdx.x;
    if (i >= IND * HID) return;
    int k = i / HID, n = i % HID;
    w1t[n * IND + k] = f2bf(w1[i]);       // W1T[n][k] = W1[k][n]
}

__global__ void prep_w2(const float* __restrict__ w2, unsigned short* __restrict__ w2t) {
    int i = blockIdx.x * blockDim.x + threadIdx.x;
    if (i >= HID * ED) return;
    int k = i / ED, n = i % ED;
    w2t[n * HID + k] = f2bf(w2[i]);       // W2T[n][k] = W2[k][n]
}

// ---------------- main fused kernel ----------------
// LDS: one 32KB buffer. First 16KB = Ae (edge bf16 tile, 64x128, swizzled)
// during GEMM1; whole 32KB = Ht (64x256, swizzled) for GEMM2. Node parts of
// the A operand are loaded straight from global into MFMA fragments (layout
// is per-lane contiguous 16B), so no gather staging phase at all.
__global__ __launch_bounds__(256, 4)
void edge_mlp(const float* __restrict__ edgef,
              const int* __restrict__ eidx,
              const unsigned short* __restrict__ nodesb,
              const unsigned short* __restrict__ w1t,
              const unsigned short* __restrict__ w2t,
              const float* __restrict__ b1,
              const float* __restrict__ b2,
              float* __restrict__ out) {
    __shared__ unsigned short smem[EB * HID];   // 32 KB
    unsigned short* Ae = smem;                  // [64][128] swizzled (first 16KB)
    unsigned short* Ht = smem;                  // [64][256] swizzled

    const int tid  = threadIdx.x;
    const int base = blockIdx.x * EB;
    const int lane = tid & 63;
    const int w    = tid >> 6;       // wave id 0..3
    const int l15  = lane & 15;
    const int lhi  = lane >> 4;      // 0..3

    // ---- per-lane edge indices for its 4 A-rows (row = mt*16 + l15) ----
    const int* srcI = eidx;
    const int* dstI = eidx + E_TOTAL;
    int sIdx[4], dIdx[4];
    #pragma unroll
    for (int mt = 0; mt < 4; ++mt) {
        int e  = base + mt * 16 + l15;
        int el = e < E_TOTAL ? e : E_TOTAL - 1;
        sIdx[mt] = srcI[el];
        dIdx[mt] = dstI[el];
    }

    // ---- stage Ae: 64x128 edge features f32 -> bf16 (coalesced) ----
    #pragma unroll
    for (int it = 0; it < 4; ++it) {
        int chunk = tid + it * 256;          // 0..1023 ; 16 chunks of 8 per row
        int row = chunk >> 4;
        int cc  = chunk & 15;
        int e   = base + row;
        int el  = e < E_TOTAL ? e : E_TOTAL - 1;
        const float* p = edgef + (size_t)el * ED + cc * 8;
        float4 f0 = *(const float4*)p;
        float4 f1 = *(const float4*)(p + 4);
        bf16x8 val;
        val[0] = (short)f2bf(f0.x); val[1] = (short)f2bf(f0.y);
        val[2] = (short)f2bf(f0.z); val[3] = (short)f2bf(f0.w);
        val[4] = (short)f2bf(f1.x); val[5] = (short)f2bf(f1.y);
        val[6] = (short)f2bf(f1.z); val[7] = (short)f2bf(f1.w);
        int col = (cc * 8) ^ ((row & 7) * 8);
        *(bf16x8*)(Ae + row * ND + col) = val;
    }
    __syncthreads();

    // ---- GEMM1: H(64x256) = [src|dst|edge](64x384) @ W1 ----
    f32x4 acc1[4][4];
    #pragma unroll
    for (int mt = 0; mt < 4; ++mt)
        #pragma unroll
        for (int nt = 0; nt < 4; ++nt)
            acc1[mt][nt] = (f32x4)0.0f;

    #pragma unroll
    for (int ks = 0; ks < 12; ++ks) {
        int c0 = ks * 32 + lhi * 8;          // k-offset within 384
        bf16x8 a[4];
        if (ks < 4) {                        // h_src: direct global gather
            #pragma unroll
            for (int mt = 0; mt < 4; ++mt)
                a[mt] = *(const bf16x8*)(nodesb + (size_t)sIdx[mt] * ND + c0);
        } else if (ks < 8) {                 // h_dst
            int c = c0 - 128;
            #pragma unroll
            for (int mt = 0; mt < 4; ++mt)
                a[mt] = *(const bf16x8*)(nodesb + (size_t)dIdx[mt] * ND + c);
        } else {                             // h_edge from LDS
            int c = c0 - 256;
            #pragma unroll
            for (int mt = 0; mt < 4; ++mt) {
                int row = mt * 16 + l15;
                a[mt] = *(const bf16x8*)(Ae + row * ND + (c ^ ((row & 7) * 8)));
            }
        }
        #pragma unroll
        for (int nt = 0; nt < 4; ++nt) {
            int n = w * 64 + nt * 16 + l15;
            bf16x8 b = *(const bf16x8*)(w1t + (size_t)n * IND + c0);
            #pragma unroll
            for (int mt = 0; mt < 4; ++mt)
                acc1[mt][nt] = __builtin_amdgcn_mfma_f32_16x16x32_bf16(a[mt], b, acc1[mt][nt], 0, 0, 0);
        }
    }
    __syncthreads();   // all Ae reads done before Ht overwrites the buffer

    // ---- bias + relu + bf16 -> Ht (swizzled) ----
    #pragma unroll
    for (int nt = 0; nt < 4; ++nt) {
        int col = w * 64 + nt * 16 + l15;
        float bias = b1[col];
        #pragma unroll
        for (int mt = 0; mt < 4; ++mt) {
            #pragma unroll
            for (int r = 0; r < 4; ++r) {
                float v = acc1[mt][nt][r] + bias;
                v = v > 0.0f ? v : 0.0f;
                int row = mt * 16 + lhi * 4 + r;
                Ht[row * HID + (col ^ ((row & 7) * 8))] = f2bf(v);
            }
        }
    }
    __syncthreads();

    // ---- GEMM2: U(64x128) = H(64x256) @ W2 ----
    f32x4 acc2[4][2];
    #pragma unroll
    for (int mt = 0; mt < 4; ++mt)
        #pragma unroll
        for (int nt = 0; nt < 2; ++nt)
            acc2[mt][nt] = (f32x4)0.0f;

    #pragma unroll
    for (int ks = 0; ks < 8; ++ks) {
        int c0 = ks * 32 + lhi * 8;
        bf16x8 a[4];
        #pragma unroll
        for (int mt = 0; mt < 4; ++mt) {
            int row = mt * 16 + l15;
            a[mt] = *(const bf16x8*)(Ht + row * HID + (c0 ^ ((row & 7) * 8)));
        }
        #pragma unroll
        for (int nt = 0; nt < 2; ++nt) {
            int n = w * 32 + nt * 16 + l15;
            bf16x8 b = *(const bf16x8*)(w2t + (size_t)n * HID + c0);
            #pragma unroll
            for (int mt = 0; mt < 4; ++mt)
                acc2[mt][nt] = __builtin_amdgcn_mfma_f32_16x16x32_bf16(a[mt], b, acc2[mt][nt], 0, 0, 0);
        }
    }

    // ---- epilogue: out = edge + update + b2 ----
    #pragma unroll
    for (int nt = 0; nt < 2; ++nt) {
        int col = w * 32 + nt * 16 + l15;
        float bias = b2[col];
        #pragma unroll
        for (int mt = 0; mt < 4; ++mt) {
            #pragma unroll
            for (int r = 0; r < 4; ++r) {
                int row = mt * 16 + lhi * 4 + r;
                int e = base + row;
                if (e < E_TOTAL) {
                    size_t off = (size_t)e * ED + col;
                    out[off] = edgef[off] + acc2[mt][nt][r] + bias;
                }
            }
        }
    }
}

extern "C" void kernel_launch(void* const* d_in, const int* in_sizes, int n_in,
                              void* d_out, int out_size, void* d_ws, size_t ws_size,
                              hipStream_t stream) {
    const float* nf   = (const float*)d_in[0];
    const float* ef   = (const float*)d_in[1];
    const int*   eidx = (const int*)d_in[2];
    const float* W1   = (const float*)d_in[3];
    const float* b1   = (const float*)d_in[4];
    const float* W2   = (const float*)d_in[5];
    const float* b2   = (const float*)d_in[6];
    float* out = (float*)d_out;

    unsigned short* nodesb = (unsigned short*)d_ws;            // 12.8 MB
    unsigned short* w1t    = nodesb + NN * ND;                 // 192 KB
    unsigned short* w2t    = w1t + IND * HID;                  // 64 KB

    prep_nodes<<<(NN * ND / 4 + 255) / 256, 256, 0, stream>>>(nf, nodesb);
    prep_w1<<<(IND * HID + 255) / 256, 256, 0, stream>>>(W1, w1t);
    prep_w2<<<(HID * ED + 255) / 256, 256, 0, stream>>>(W2, w2t);
    edge_mlp<<<NBLOCKS, 256, 0, stream>>>(ef, eidx, nodesb, w1t, w2t, b1, b2, out);
}

// Round 3
// 289.633 us; speedup vs baseline: 2.1543x; 1.5980x over previous
//
#include <hip/hip_runtime.h>

#define E_TOTAL   500000
#define NN        50000
#define ND        128
#define ED        128
#define HID       256
#define IND       384   /* 2*ND + ED */
#define EB        64
#define NBLOCKS   ((E_TOTAL + EB - 1) / EB)

typedef float  f32x4  __attribute__((ext_vector_type(4)));
typedef short  bf16x8 __attribute__((ext_vector_type(8)));

__device__ __forceinline__ unsigned short f2bf(float f) {
    unsigned int u = __float_as_uint(f);
    u += 0x7FFFu + ((u >> 16) & 1u);   // RNE
    return (unsigned short)(u >> 16);
}
__device__ __forceinline__ float bf2f(unsigned short h) {
    return __uint_as_float(((unsigned int)h) << 16);
}

// ---------------- prep: weights fp32 -> bf16 transposed ----------------
__global__ void prep_w1(const float* __restrict__ w1, unsigned short* __restrict__ w1t) {
    int i = blockIdx.x * blockDim.x + threadIdx.x;
    if (i >= IND * HID) return;
    int k = i / HID, n = i % HID;
    w1t[n * IND + k] = f2bf(w1[i]);       // W1T[n][k] = W1[k][n]
}

__global__ void prep_w2(const float* __restrict__ w2, unsigned short* __restrict__ w2t) {
    int i = blockIdx.x * blockDim.x + threadIdx.x;
    if (i >= HID * ED) return;
    int k = i / ED, n = i % ED;
    w2t[n * HID + k] = f2bf(w2[i]);       // W2T[n][k] = W2[k][n]
}

// ---------------- prep: per-node partial products ----------------
// Psrc[n][:] = nodes[n] @ W1[0:128, :] + b1   (bf16, 50000x256)
// Pdst[n][:] = nodes[n] @ W1[128:256, :]      (bf16, 50000x256)
__global__ __launch_bounds__(256, 2)
void prep_ptab(const float* __restrict__ nf,
               const unsigned short* __restrict__ w1t,
               const float* __restrict__ b1,
               unsigned short* __restrict__ Psrc,
               unsigned short* __restrict__ Pdst) {
    __shared__ unsigned short An[EB * ND];   // 16 KB swizzled
    const int tid  = threadIdx.x;
    const int base = blockIdx.x * EB;
    const int lane = tid & 63;
    const int w    = tid >> 6;
    const int l15  = lane & 15;
    const int lhi  = lane >> 4;

    #pragma unroll
    for (int it = 0; it < 4; ++it) {
        int item = tid + it * 256;          // 0..1023
        int row = item >> 4, cc = item & 15;
        int nidx = base + row;
        if (nidx >= NN) nidx = NN - 1;
        const float* p = nf + (size_t)nidx * ND + cc * 8;
        float4 f0 = *(const float4*)p;
        float4 f1 = *(const float4*)(p + 4);
        bf16x8 val;
        val[0] = (short)f2bf(f0.x); val[1] = (short)f2bf(f0.y);
        val[2] = (short)f2bf(f0.z); val[3] = (short)f2bf(f0.w);
        val[4] = (short)f2bf(f1.x); val[5] = (short)f2bf(f1.y);
        val[6] = (short)f2bf(f1.z); val[7] = (short)f2bf(f1.w);
        *(bf16x8*)(An + row * ND + ((cc * 8) ^ ((row & 7) * 8))) = val;
    }
    __syncthreads();

    f32x4 accs[4][4], accd[4][4];
    #pragma unroll
    for (int mt = 0; mt < 4; ++mt)
        #pragma unroll
        for (int nt = 0; nt < 4; ++nt) { accs[mt][nt] = (f32x4)0.0f; accd[mt][nt] = (f32x4)0.0f; }

    #pragma unroll
    for (int ks = 0; ks < 4; ++ks) {
        int c0 = ks * 32 + lhi * 8;
        bf16x8 a[4];
        #pragma unroll
        for (int mt = 0; mt < 4; ++mt) {
            int row = mt * 16 + l15;
            a[mt] = *(const bf16x8*)(An + row * ND + (c0 ^ ((row & 7) * 8)));
        }
        #pragma unroll
        for (int nt = 0; nt < 4; ++nt) {
            int n = w * 64 + nt * 16 + l15;
            bf16x8 bs = *(const bf16x8*)(w1t + (size_t)n * IND + c0);         // W1 rows 0:128
            bf16x8 bd = *(const bf16x8*)(w1t + (size_t)n * IND + 128 + c0);   // W1 rows 128:256
            #pragma unroll
            for (int mt = 0; mt < 4; ++mt) {
                accs[mt][nt] = __builtin_amdgcn_mfma_f32_16x16x32_bf16(a[mt], bs, accs[mt][nt], 0, 0, 0);
                accd[mt][nt] = __builtin_amdgcn_mfma_f32_16x16x32_bf16(a[mt], bd, accd[mt][nt], 0, 0, 0);
            }
        }
    }

    #pragma unroll
    for (int nt = 0; nt < 4; ++nt) {
        int col = w * 64 + nt * 16 + l15;
        float bias = b1[col];
        #pragma unroll
        for (int mt = 0; mt < 4; ++mt) {
            #pragma unroll
            for (int r = 0; r < 4; ++r) {
                int row = mt * 16 + lhi * 4 + r;
                int nidx = base + row;
                if (nidx < NN) {
                    size_t off = (size_t)nidx * HID + col;
                    Psrc[off] = f2bf(accs[mt][nt][r] + bias);
                    Pdst[off] = f2bf(accd[mt][nt][r]);
                }
            }
        }
    }
}

// ---------------- main fused kernel ----------------
// LDS: Ae [64][128] bf16 swizzled (edge features, also residual source),
//      Hs [64][256] bf16 swizzled (Psrc[src]+Pdst[dst] gathered sum; updated
//      in place with +GEMM1edge +relu, then read as GEMM2's A-tile).
__global__ __launch_bounds__(256, 3)
void edge_mlp(const float* __restrict__ edgef,
              const int* __restrict__ eidx,
              const unsigned short* __restrict__ Psrc,
              const unsigned short* __restrict__ Pdst,
              const unsigned short* __restrict__ w1t,
              const unsigned short* __restrict__ w2t,
              const float* __restrict__ b2,
              float* __restrict__ out) {
    __shared__ unsigned short Ae[EB * ND];    // 16 KB
    __shared__ unsigned short Hs[EB * HID];   // 32 KB

    const int tid  = threadIdx.x;
    const int base = blockIdx.x * EB;
    const int lane = tid & 63;
    const int w    = tid >> 6;
    const int l15  = lane & 15;
    const int lhi  = lane >> 4;
    const int* srcI = eidx;
    const int* dstI = eidx + E_TOTAL;

    // ---- stage Ae: 64x128 edge features f32 -> bf16 (coalesced) ----
    #pragma unroll
    for (int it = 0; it < 4; ++it) {
        int item = tid + it * 256;           // 0..1023
        int row = item >> 4, cc = item & 15;
        int e = base + row;
        int el = e < E_TOTAL ? e : E_TOTAL - 1;
        const float* p = edgef + (size_t)el * ED + cc * 8;
        float4 f0 = *(const float4*)p;
        float4 f1 = *(const float4*)(p + 4);
        bf16x8 val;
        val[0] = (short)f2bf(f0.x); val[1] = (short)f2bf(f0.y);
        val[2] = (short)f2bf(f0.z); val[3] = (short)f2bf(f0.w);
        val[4] = (short)f2bf(f1.x); val[5] = (short)f2bf(f1.y);
        val[6] = (short)f2bf(f1.z); val[7] = (short)f2bf(f1.w);
        *(bf16x8*)(Ae + row * ND + ((cc * 8) ^ ((row & 7) * 8))) = val;
    }

    // ---- stage Hs: Hs[row][:] = Psrc[src[row]][:] + Pdst[dst[row]][:] ----
    #pragma unroll
    for (int it = 0; it < 8; ++it) {
        int item = tid + it * 256;           // 0..2047
        int row = item >> 5, cc = item & 31;
        int e = base + row;
        int el = e < E_TOTAL ? e : E_TOTAL - 1;
        int s = srcI[el], d = dstI[el];
        bf16x8 vs = *(const bf16x8*)(Psrc + (size_t)s * HID + cc * 8);
        bf16x8 vd = *(const bf16x8*)(Pdst + (size_t)d * HID + cc * 8);
        bf16x8 o;
        #pragma unroll
        for (int j = 0; j < 8; ++j)
            o[j] = (short)f2bf(bf2f((unsigned short)vs[j]) + bf2f((unsigned short)vd[j]));
        *(bf16x8*)(Hs + row * HID + ((cc * 8) ^ ((row & 7) * 8))) = o;
    }
    __syncthreads();

    // ---- GEMM1-edge: acc1(64x256) = Ae(64x128) @ W1[256:384,:] ----
    f32x4 acc1[4][4];
    #pragma unroll
    for (int mt = 0; mt < 4; ++mt)
        #pragma unroll
        for (int nt = 0; nt < 4; ++nt)
            acc1[mt][nt] = (f32x4)0.0f;

    #pragma unroll
    for (int ks = 0; ks < 4; ++ks) {
        int c0 = ks * 32 + lhi * 8;
        bf16x8 a[4];
        #pragma unroll
        for (int mt = 0; mt < 4; ++mt) {
            int row = mt * 16 + l15;
            a[mt] = *(const bf16x8*)(Ae + row * ND + (c0 ^ ((row & 7) * 8)));
        }
        #pragma unroll
        for (int nt = 0; nt < 4; ++nt) {
            int n = w * 64 + nt * 16 + l15;
            bf16x8 b = *(const bf16x8*)(w1t + (size_t)n * IND + 256 + c0);
            #pragma unroll
            for (int mt = 0; mt < 4; ++mt)
                acc1[mt][nt] = __builtin_amdgcn_mfma_f32_16x16x32_bf16(a[mt], b, acc1[mt][nt], 0, 0, 0);
        }
    }

    // ---- h = relu(Hs + acc1) -> Hs in place (b1 already folded in Psrc) ----
    #pragma unroll
    for (int nt = 0; nt < 4; ++nt) {
        int col = w * 64 + nt * 16 + l15;
        #pragma unroll
        for (int mt = 0; mt < 4; ++mt) {
            #pragma unroll
            for (int r = 0; r < 4; ++r) {
                int row = mt * 16 + lhi * 4 + r;
                int idx = row * HID + (col ^ ((row & 7) * 8));
                float v = acc1[mt][nt][r] + bf2f(Hs[idx]);
                v = v > 0.0f ? v : 0.0f;
                Hs[idx] = f2bf(v);
            }
        }
    }
    __syncthreads();

    // ---- GEMM2: U(64x128) = Hs(64x256) @ W2 ----
    f32x4 acc2[4][2];
    #pragma unroll
    for (int mt = 0; mt < 4; ++mt)
        #pragma unroll
        for (int nt = 0; nt < 2; ++nt)
            acc2[mt][nt] = (f32x4)0.0f;

    #pragma unroll
    for (int ks = 0; ks < 8; ++ks) {
        int c0 = ks * 32 + lhi * 8;
        bf16x8 a[4];
        #pragma unroll
        for (int mt = 0; mt < 4; ++mt) {
            int row = mt * 16 + l15;
            a[mt] = *(const bf16x8*)(Hs + row * HID + (c0 ^ ((row & 7) * 8)));
        }
        #pragma unroll
        for (int nt = 0; nt < 2; ++nt) {
            int n = w * 32 + nt * 16 + l15;
            bf16x8 b = *(const bf16x8*)(w2t + (size_t)n * HID + c0);
            #pragma unroll
            for (int mt = 0; mt < 4; ++mt)
                acc2[mt][nt] = __builtin_amdgcn_mfma_f32_16x16x32_bf16(a[mt], b, acc2[mt][nt], 0, 0, 0);
        }
    }

    // ---- epilogue: out = Ae(bf16 edge) + update + b2 ----
    #pragma unroll
    for (int nt = 0; nt < 2; ++nt) {
        int col = w * 32 + nt * 16 + l15;
        float bias = b2[col];
        #pragma unroll
        for (int mt = 0; mt < 4; ++mt) {
            #pragma unroll
            for (int r = 0; r < 4; ++r) {
                int row = mt * 16 + lhi * 4 + r;
                int e = base + row;
                if (e < E_TOTAL) {
                    float ev = bf2f(Ae[row * ND + (col ^ ((row & 7) * 8))]);
                    out[(size_t)e * ED + col] = ev + acc2[mt][nt][r] + bias;
                }
            }
        }
    }
}

extern "C" void kernel_launch(void* const* d_in, const int* in_sizes, int n_in,
                              void* d_out, int out_size, void* d_ws, size_t ws_size,
                              hipStream_t stream) {
    const float* nf   = (const float*)d_in[0];
    const float* ef   = (const float*)d_in[1];
    const int*   eidx = (const int*)d_in[2];
    const float* W1   = (const float*)d_in[3];
    const float* b1   = (const float*)d_in[4];
    const float* W2   = (const float*)d_in[5];
    const float* b2   = (const float*)d_in[6];
    float* out = (float*)d_out;

    unsigned short* w1t  = (unsigned short*)d_ws;          // 192 KB
    unsigned short* w2t  = w1t + IND * HID;                // 64 KB
    unsigned short* Psrc = w2t + HID * ED;                 // 25.6 MB
    unsigned short* Pdst = Psrc + (size_t)NN * HID;        // 25.6 MB

    prep_w1<<<(IND * HID + 255) / 256, 256, 0, stream>>>(W1, w1t);
    prep_w2<<<(HID * ED + 255) / 256, 256, 0, stream>>>(W2, w2t);
    prep_ptab<<<(NN + EB - 1) / EB, 256, 0, stream>>>(nf, w1t, b1, Psrc, Pdst);
    edge_mlp<<<NBLOCKS, 256, 0, stream>>>(ef, eidx, Psrc, Pdst, w1t, w2t, b2, out);
}